// Round 19
// baseline (106.152 us; speedup 1.0000x reference)
//
#include <hip/hip_runtime.h>

// SAGEConv (mean aggr, root weight, L2 normalize), fp32 in/out.
// R19: fp8-e4m3 gather table (halves the L2-miss-bound gather traffic);
//      cursor zeroing folded into mega2 (no memset dispatch). 3 dispatches:
//      mega2(prep+partition) -> fillp(XCD-local ELL) -> gm(gather+MFMA).

typedef __attribute__((ext_vector_type(8))) short short8;   // 8 bf16 = 4 VGPRs
typedef __attribute__((ext_vector_type(4))) float floatx4;  // MFMA acc
typedef __attribute__((ext_vector_type(2))) float floatx2;  // fp8 cvt result

constexpr int kNodes = 50000;
constexpr int kEdges = 800000;
constexpr int kF = 96;          // input features
constexpr int kH = 128;         // output features
constexpr int kEllW = 32;       // ELL width
constexpr int kSpillCap = 4096;
constexpr int kBktRange = kNodes / 8;  // 6250 nodes per XCD-group
constexpr int kCurStride = 16;  // cursor stride in ints: 1 counter per 64B line
constexpr int kChunksP = 782;   // partition chunks (1024 edges each)
constexpr int kStgCap = 192;    // per-(chunk,bucket) cap (mean 128 + 6 sigma)

// workspace byte offsets (total 25.70 MB — same footprint as R16-R18)
constexpr size_t kXhOff    = 0;          // 9,600,000  bf16 table (MFMA x-half)
constexpr size_t kXqOff    = 9600000;    // 4,800,000  fp8 table (gather)
constexpr size_t kStgOff   = 14400000;   // 4,804,608  partition staging
constexpr size_t kWhOff    = 19204608;   // 49,152     bf16 weights
constexpr size_t kEllOff   = 19253760;   // 3,200,000  ELL (ushort)
constexpr size_t kCurOff   = 22453760;   // 3,200,000  padded cursor
constexpr size_t kSpcOff   = 25653760;   // 4          spillCnt
constexpr size_t kSpillOff = 25653776;   // 16,384     spill list
constexpr size_t kCntOff   = 25670160;   // 25,024     per-(chunk,bucket) counts

// mega2: period-4 interleave (1 partition + 3 prep), 782 periods
constexpr int kMega2Blocks = kChunksP * 4;        // 3128
constexpr int kPrepBlocks  = kChunksP * 3;        // 2346
constexpr int kPrepItems   = kNodes * kF / 8 + kH * 192 / 8;  // 603072
constexpr int kPrepStride  = kPrepBlocks * 256;   // 600576

constexpr int kRowS = 104;   // LDS agg row stride in shorts (208 B)

__device__ __forceinline__ unsigned pack2_bf16(float a, float b) {
  unsigned ua = __float_as_uint(a), ub = __float_as_uint(b);
  ua = (ua + 0x7fffu + ((ua >> 16) & 1u)) >> 16;   // RNE
  ub = (ub + 0x7fffu + ((ub >> 16) & 1u)) >> 16;
  return ua | (ub << 16);
}

// decode 16 fp8 (one uint4) and accumulate into a[0..15]
__device__ __forceinline__ void acc16_fp8(const uint4 v, float* a) {
  floatx2 f;
  f = __builtin_amdgcn_cvt_pk_f32_fp8((int)v.x, false); a[0] += f.x; a[1] += f.y;
  f = __builtin_amdgcn_cvt_pk_f32_fp8((int)v.x, true);  a[2] += f.x; a[3] += f.y;
  f = __builtin_amdgcn_cvt_pk_f32_fp8((int)v.y, false); a[4] += f.x; a[5] += f.y;
  f = __builtin_amdgcn_cvt_pk_f32_fp8((int)v.y, true);  a[6] += f.x; a[7] += f.y;
  f = __builtin_amdgcn_cvt_pk_f32_fp8((int)v.z, false); a[8] += f.x; a[9] += f.y;
  f = __builtin_amdgcn_cvt_pk_f32_fp8((int)v.z, true);  a[10] += f.x; a[11] += f.y;
  f = __builtin_amdgcn_cvt_pk_f32_fp8((int)v.w, false); a[12] += f.x; a[13] += f.y;
  f = __builtin_amdgcn_cvt_pk_f32_fp8((int)v.w, true);  a[14] += f.x; a[15] += f.y;
}

// ELL row slot-transposed for 8 slots: entry j at (j&7)*4 + (j>>3); slot s's
// 4 entries (j = 8k+s, k=0..3) are the contiguous ushorts [s*4, s*4+4).
__device__ __forceinline__ void ell_insert(int dst, int src, int* cursor,
                                           ushort* ell, unsigned* spill,
                                           int* spillCnt) {
  const int slot = atomicAdd(&cursor[(size_t)dst * kCurStride], 1);
  if (slot < kEllW) {
    ell[(size_t)dst * kEllW + ((slot & 7) << 2) + (slot >> 3)] = (ushort)src;
  } else {
    const int sp = atomicAdd(spillCnt, 1);
    if (sp < kSpillCap) spill[sp] = ((unsigned)dst << 16) | (unsigned)src;
  }
}

// --- mega2: partition (+cursor zero) || prep (bf16 + fp8 pack) ---------------
__global__ void __launch_bounds__(256)
mega2_kernel(const int* __restrict__ ei, const float* __restrict__ x,
             const float* __restrict__ Wl, const float* __restrict__ Wr,
             uint4* __restrict__ xh4, uint2* __restrict__ xq2,
             uint4* __restrict__ wh4, unsigned* __restrict__ stg,
             int* __restrict__ cnt, int* __restrict__ cursor,
             unsigned* __restrict__ spill, int* __restrict__ spillCnt) {
  const int p = blockIdx.x >> 2;
  const int r = blockIdx.x & 3;
  if (r == 0) {
    // zero padded cursor (200000 uint4 over 782x256 threads) + spillCnt
    const int zi = p * 256 + threadIdx.x;
    if (zi < 200000) reinterpret_cast<uint4*>(cursor)[zi] = make_uint4(0, 0, 0, 0);
    if (zi == 0) *spillCnt = 0;
    // ---- partition chunk p via LDS counters (no global contention) ----
    __shared__ int lcnt[8];
    if (threadIdx.x < 8) lcnt[threadIdx.x] = 0;
    __syncthreads();
    const int base = p * 1024 + threadIdx.x;
    int d[4], s[4];
#pragma unroll
    for (int k = 0; k < 4; ++k) {
      const int e = base + k * 256;
      const bool v = e < kEdges;
      d[k] = v ? ei[kEdges + e] : -1;
      s[k] = v ? ei[e] : 0;
    }
#pragma unroll
    for (int k = 0; k < 4; ++k) {
      if (d[k] >= 0) {
        const int b = d[k] / kBktRange;
        const int pos = atomicAdd(&lcnt[b], 1);
        if (pos < kStgCap) {
          stg[((size_t)p * 8 + b) * kStgCap + pos] =
              ((unsigned)d[k] << 16) | (unsigned)s[k];
        } else {  // ~impossible (6 sigma); spill-only (no cursor race)
          const int sp = atomicAdd(spillCnt, 1);
          if (sp < kSpillCap)
            spill[sp] = ((unsigned)d[k] << 16) | (unsigned)s[k];
        }
      }
    }
    __syncthreads();
    if (threadIdx.x < 8)
      cnt[p * 8 + threadIdx.x] = min(lcnt[threadIdx.x], kStgCap);
    return;
  }
  // ---- prep: bf16 + fp8 pack of x, bf16 pack of W=[Wl|Wr] ----
  constexpr int kCvt = kNodes * kF / 8;     // 600000
  const int pid = p * 3 + (r - 1);          // 0..2345
  for (int i = pid * 256 + threadIdx.x; i < kPrepItems; i += kPrepStride) {
    if (i < kCvt) {
      const float4 v0 = reinterpret_cast<const float4*>(x)[i * 2];
      const float4 v1 = reinterpret_cast<const float4*>(x)[i * 2 + 1];
      uint4 o;
      o.x = pack2_bf16(v0.x, v0.y);
      o.y = pack2_bf16(v0.z, v0.w);
      o.z = pack2_bf16(v1.x, v1.y);
      o.w = pack2_bf16(v1.z, v1.w);
      xh4[i] = o;
      int u0 = __builtin_amdgcn_cvt_pk_fp8_f32(v0.x, v0.y, 0, false);
      u0 = __builtin_amdgcn_cvt_pk_fp8_f32(v0.z, v0.w, u0, true);
      int u1 = __builtin_amdgcn_cvt_pk_fp8_f32(v1.x, v1.y, 0, false);
      u1 = __builtin_amdgcn_cvt_pk_fp8_f32(v1.z, v1.w, u1, true);
      xq2[i] = make_uint2((unsigned)u0, (unsigned)u1);
    } else {
      const int j = i - kCvt;
      const int row = j / 24, chunk = j % 24;
      const float* src = (chunk < 12) ? (Wl + (size_t)row * kF + chunk * 8)
                                      : (Wr + (size_t)row * kF + (chunk - 12) * 8);
      const float4 v0 = reinterpret_cast<const float4*>(src)[0];
      const float4 v1 = reinterpret_cast<const float4*>(src)[1];
      uint4 o;
      o.x = pack2_bf16(v0.x, v0.y);
      o.y = pack2_bf16(v0.z, v0.w);
      o.z = pack2_bf16(v1.x, v1.y);
      o.w = pack2_bf16(v1.z, v1.w);
      wh4[j] = o;
    }
  }
}

// --- fillp: XCD-aligned ELL build from compacted lists -----------------------
__global__ void __launch_bounds__(256)
fillp_kernel(const unsigned* __restrict__ stg, const int* __restrict__ cnt,
             int* __restrict__ cursor, ushort* __restrict__ ell,
             unsigned* __restrict__ spill, int* __restrict__ spillCnt) {
  const int g = blockIdx.x & 7;
  for (int chunk = blockIdx.x >> 3; chunk < kChunksP; chunk += gridDim.x >> 3) {
    const int n = cnt[chunk * 8 + g];
    const unsigned* reg = stg + ((size_t)chunk * 8 + g) * kStgCap;
    for (int i = threadIdx.x; i < n; i += 256) {
      const unsigned pr = reg[i];
      ell_insert((int)(pr >> 16), (int)(pr & 0xffffu), cursor, ell, spill,
                 spillCnt);
    }
  }
}

// --- fused gather(fp8) + MFMA, 4 waves per 16-node tile ----------------------
// Gather: 8 edge-slots x 6 chunk-lanes (48 lanes), 16 fp8 feats per lane.
// Per wave: 4 nodes in 2 rounds of 2. Combine tree: +24, +12, +6.
__global__ void __launch_bounds__(256)
gm_kernel(const uint4* __restrict__ xq4, const uint4* __restrict__ xh4,
          const int* __restrict__ cursor, const ushort* __restrict__ ell,
          const unsigned* __restrict__ spill, const int* __restrict__ spillCnt,
          const uint4* __restrict__ wh4, const float* __restrict__ bl,
          float* __restrict__ out) {
  __shared__ __align__(16) short sAgg[16 * kRowS];   // 16 rows x 208 B
  __shared__ float sP[4][4][4];                      // [wave][q][reg]

  const int wave = threadIdx.x >> 6, lane = threadIdx.x & 63;
  const int g = blockIdx.x & 7;
  const int j = blockIdx.x >> 3;
  const int tstart = (g * 3125) >> 3;
  const int tend = ((g + 1) * 3125) >> 3;
  const int tile = tstart + j;
  if (tile >= tend) return;
  const int base = tile * 16;

  const int slot = lane / 6;     // 0..7 for lanes 0..47
  const int c = lane % 6;        // 16-feat chunk
  const bool gactive = lane < 48;
  const int slotc = gactive ? slot : 0;
  const int sc = min(*spillCnt, kSpillCap);  // ~always 0

#pragma unroll
  for (int it = 0; it < 2; ++it) {
    const int nA = base + wave * 4 + it * 2;
    const int nB = nA + 1;
    const int degA = cursor[(size_t)nA * kCurStride];
    const int degB = cursor[(size_t)nB * kCurStride];
    const int dmA = min(degA, kEllW);
    const int dmB = min(degB, kEllW);

    // 8B index load per node: slot s's 4 entries = ushorts [s*4, s*4+4)
    const uint2 iA = *reinterpret_cast<const uint2*>(
        ell + (size_t)nA * kEllW + (slotc << 2));
    const uint2 iB = *reinterpret_cast<const uint2*>(
        ell + (size_t)nB * kEllW + (slotc << 2));

    float a[16], b[16];
#pragma unroll
    for (int f = 0; f < 16; ++f) { a[f] = 0.f; b[f] = 0.f; }

#pragma unroll
    for (int k = 0; k < 4; ++k) {
      const int idx = (k << 3) + slot;   // original ELL position
      const unsigned wA = (k < 2) ? iA.x : iA.y;
      const unsigned wB = (k < 2) ? iB.x : iB.y;
      const int srcA = (k & 1) ? (int)(wA >> 16) : (int)(wA & 0xffffu);
      const int srcB = (k & 1) ? (int)(wB >> 16) : (int)(wB & 0xffffu);
      if (gactive && idx < dmA) acc16_fp8(xq4[(size_t)srcA * 6 + c], a);
      if (gactive && idx < dmB) acc16_fp8(xq4[(size_t)srcB * 6 + c], b);
    }
    // spill edges (rare)
    for (int jj = 0; jj < sc; ++jj) {
      const unsigned pr = spill[jj];
      const int pd = (int)(pr >> 16);
      if (lane < 6 && (pd == nA || pd == nB)) {
        const uint4 v = xq4[(size_t)(pr & 0xffffu) * 6 + c];
        if (pd == nA) acc16_fp8(v, a); else acc16_fp8(v, b);
      }
    }
    // combine 8 slots -> lanes 0..5 (3 rounds)
#pragma unroll
    for (int f = 0; f < 16; ++f) {
      a[f] += __shfl(a[f], lane + 24, 64);
      b[f] += __shfl(b[f], lane + 24, 64);
    }
#pragma unroll
    for (int f = 0; f < 16; ++f) {
      a[f] += __shfl(a[f], lane + 12, 64);
      b[f] += __shfl(b[f], lane + 12, 64);
    }
#pragma unroll
    for (int f = 0; f < 16; ++f) {
      a[f] += __shfl(a[f], lane + 6, 64);
      b[f] += __shfl(b[f], lane + 6, 64);
    }

    if (lane < 6) {
      const float invA = 1.0f / fmaxf((float)degA, 1.0f);
      const float invB = 1.0f / fmaxf((float)degB, 1.0f);
      short* rowA = &sAgg[(wave * 4 + it * 2) * kRowS + c * 16];
      short* rowB = &sAgg[(wave * 4 + it * 2 + 1) * kRowS + c * 16];
      uint4 oa, ob;
      oa.x = pack2_bf16(a[0] * invA, a[1] * invA);
      oa.y = pack2_bf16(a[2] * invA, a[3] * invA);
      oa.z = pack2_bf16(a[4] * invA, a[5] * invA);
      oa.w = pack2_bf16(a[6] * invA, a[7] * invA);
      *reinterpret_cast<uint4*>(rowA) = oa;
      oa.x = pack2_bf16(a[8] * invA, a[9] * invA);
      oa.y = pack2_bf16(a[10] * invA, a[11] * invA);
      oa.z = pack2_bf16(a[12] * invA, a[13] * invA);
      oa.w = pack2_bf16(a[14] * invA, a[15] * invA);
      *reinterpret_cast<uint4*>(rowA + 8) = oa;
      ob.x = pack2_bf16(b[0] * invB, b[1] * invB);
      ob.y = pack2_bf16(b[2] * invB, b[3] * invB);
      ob.z = pack2_bf16(b[4] * invB, b[5] * invB);
      ob.w = pack2_bf16(b[6] * invB, b[7] * invB);
      *reinterpret_cast<uint4*>(rowB) = ob;
      ob.x = pack2_bf16(b[8] * invB, b[9] * invB);
      ob.y = pack2_bf16(b[10] * invB, b[11] * invB);
      ob.z = pack2_bf16(b[12] * invB, b[13] * invB);
      ob.w = pack2_bf16(b[14] * invB, b[15] * invB);
      *reinterpret_cast<uint4*>(rowB + 8) = ob;
    }
  }
  __syncthreads();

  // ---- phase B: MFMA, wave w owns channel-groups {2w, 2w+1} ----
  const int r = lane & 15, q = lane >> 4;
  const int cg0 = wave * 2;
  const short8* xhS = reinterpret_cast<const short8*>(xh4);
  const short8* whS = reinterpret_cast<const short8*>(wh4);

  floatx4 fac[2] = {};
#pragma unroll
  for (int ks = 0; ks < 6; ++ks) {
    short8 a;
    if (ks < 3) {
      a = *reinterpret_cast<const short8*>(&sAgg[r * kRowS + (ks * 4 + q) * 8]);
    } else {
      a = xhS[(size_t)(base + r) * 12 + (ks - 3) * 4 + q];
    }
#pragma unroll
    for (int i = 0; i < 2; ++i) {
      const short8 b = whS[((cg0 + i) * 16 + r) * 24 + ks * 4 + q];
      fac[i] = __builtin_amdgcn_mfma_f32_16x16x32_bf16(a, b, fac[i], 0, 0, 0);
    }
  }

  float p0 = 0.f, p1 = 0.f, p2 = 0.f, p3 = 0.f;
#pragma unroll
  for (int i = 0; i < 2; ++i) {
    const float bb = bl[(cg0 + i) * 16 + r];
    fac[i][0] += bb; fac[i][1] += bb; fac[i][2] += bb; fac[i][3] += bb;
    p0 += fac[i][0] * fac[i][0];
    p1 += fac[i][1] * fac[i][1];
    p2 += fac[i][2] * fac[i][2];
    p3 += fac[i][3] * fac[i][3];
  }
#pragma unroll
  for (int off = 1; off < 16; off <<= 1) {
    p0 += __shfl_xor(p0, off, 64);
    p1 += __shfl_xor(p1, off, 64);
    p2 += __shfl_xor(p2, off, 64);
    p3 += __shfl_xor(p3, off, 64);
  }
  if (r == 0) {
    sP[wave][q][0] = p0; sP[wave][q][1] = p1;
    sP[wave][q][2] = p2; sP[wave][q][3] = p3;
  }
  __syncthreads();
  const float t0 = sP[0][q][0] + sP[1][q][0] + sP[2][q][0] + sP[3][q][0];
  const float t1 = sP[0][q][1] + sP[1][q][1] + sP[2][q][1] + sP[3][q][1];
  const float t2 = sP[0][q][2] + sP[1][q][2] + sP[2][q][2] + sP[3][q][2];
  const float t3 = sP[0][q][3] + sP[1][q][3] + sP[2][q][3] + sP[3][q][3];
  const float s0 = 1.0f / fmaxf(sqrtf(t0), 1e-12f);
  const float s1 = 1.0f / fmaxf(sqrtf(t1), 1e-12f);
  const float s2 = 1.0f / fmaxf(sqrtf(t2), 1e-12f);
  const float s3 = 1.0f / fmaxf(sqrtf(t3), 1e-12f);

#pragma unroll
  for (int i = 0; i < 2; ++i) {
    const int col = (cg0 + i) * 16 + r;
    float* o = out + (size_t)(base + q * 4) * kH + col;
    o[0 * kH] = fac[i][0] * s0;
    o[1 * kH] = fac[i][1] * s1;
    o[2 * kH] = fac[i][2] * s2;
    o[3 * kH] = fac[i][3] * s3;
  }
}

extern "C" void kernel_launch(void* const* d_in, const int* in_sizes, int n_in,
                              void* d_out, int out_size, void* d_ws, size_t ws_size,
                              hipStream_t stream) {
  const int*   ei = (const int*)d_in[0];
  const float* x  = (const float*)d_in[1];
  const float* Wl = (const float*)d_in[2];
  const float* bl = (const float*)d_in[3];
  const float* Wr = (const float*)d_in[4];
  float* out = (float*)d_out;

  char* ws = (char*)d_ws;
  uint4*    xh4      = (uint4*)(ws + kXhOff);
  uint2*    xq2      = (uint2*)(ws + kXqOff);
  uint4*    xq4      = (uint4*)(ws + kXqOff);
  unsigned* stg      = (unsigned*)(ws + kStgOff);
  uint4*    wh4      = (uint4*)(ws + kWhOff);
  ushort*   ell      = (ushort*)(ws + kEllOff);
  int*      cursor   = (int*)(ws + kCurOff);
  int*      spillCnt = (int*)(ws + kSpcOff);
  unsigned* spill    = (unsigned*)(ws + kSpillOff);
  int*      cnt      = (int*)(ws + kCntOff);

  mega2_kernel<<<kMega2Blocks, 256, 0, stream>>>(
      ei, x, Wl, Wr, xh4, xq2, wh4, stg, cnt, cursor, spill, spillCnt);

  fillp_kernel<<<3128, 256, 0, stream>>>(stg, cnt, cursor, ell, spill, spillCnt);

  gm_kernel<<<3128, 256, 0, stream>>>(xq4, xh4, cursor, ell, spill, spillCnt,
                                      wh4, bl, out);
}

// Round 20
// 96.497 us; speedup vs baseline: 1.1001x; 1.1001x over previous
//
#include <hip/hip_runtime.h>

// SAGEConv (mean aggr, root weight, L2 normalize), fp32 in/out.
// R20: fp8 gather payload in R15's PROVEN lane geometry (4 slots x 12 lanes,
//      8 acc/node -> VGPR ~36, occupancy ~60%) — R19 kept the traffic halving
//      but lost occupancy; this keeps both. 3 dispatches.

typedef __attribute__((ext_vector_type(8))) short short8;   // 8 bf16 = 4 VGPRs
typedef __attribute__((ext_vector_type(4))) float floatx4;  // MFMA acc
typedef __attribute__((ext_vector_type(2))) float floatx2;  // fp8 cvt result

constexpr int kNodes = 50000;
constexpr int kEdges = 800000;
constexpr int kF = 96;          // input features
constexpr int kH = 128;         // output features
constexpr int kEllW = 32;       // ELL width
constexpr int kSpillCap = 4096;
constexpr int kBktRange = kNodes / 8;  // 6250 nodes per XCD-group
constexpr int kCurStride = 16;  // cursor stride in ints: 1 counter per 64B line
constexpr int kChunksP = 782;   // partition chunks (1024 edges each)
constexpr int kStgCap = 192;    // per-(chunk,bucket) cap (mean 128 + 6 sigma)

// workspace byte offsets
constexpr size_t kXhOff    = 0;          // 9,600,000  bf16 table (MFMA x-half)
constexpr size_t kXqOff    = 9600000;    // 4,800,000  fp8 table (gather)
constexpr size_t kStgOff   = 14400000;   // 4,804,608  partition staging
constexpr size_t kWhOff    = 19204608;   // 49,152     bf16 weights
constexpr size_t kEllOff   = 19253760;   // 3,200,000  ELL (ushort)
constexpr size_t kCurOff   = 22453760;   // 3,200,000  padded cursor
constexpr size_t kSpcOff   = 25653760;   // 4          spillCnt
constexpr size_t kSpillOff = 25653776;   // 16,384     spill list
constexpr size_t kCntOff   = 25670160;   // 25,024     per-(chunk,bucket) counts

// mega2: period-4 interleave (1 partition + 3 prep), 782 periods
constexpr int kMega2Blocks = kChunksP * 4;        // 3128
constexpr int kPrepBlocks  = kChunksP * 3;        // 2346
constexpr int kPrepItems   = kNodes * kF / 8 + kH * 192 / 8;  // 603072
constexpr int kPrepStride  = kPrepBlocks * 256;   // 600576

constexpr int kRowS = 104;   // LDS agg row stride in shorts (208 B)

__device__ __forceinline__ unsigned pack2_bf16(float a, float b) {
  unsigned ua = __float_as_uint(a), ub = __float_as_uint(b);
  ua = (ua + 0x7fffu + ((ua >> 16) & 1u)) >> 16;   // RNE
  ub = (ub + 0x7fffu + ((ub >> 16) & 1u)) >> 16;
  return ua | (ub << 16);
}

// decode 8 fp8 (one uint2) and accumulate into a[0..7]
__device__ __forceinline__ void acc8_fp8(const uint2 v, float* a) {
  floatx2 f;
  f = __builtin_amdgcn_cvt_pk_f32_fp8((int)v.x, false); a[0] += f.x; a[1] += f.y;
  f = __builtin_amdgcn_cvt_pk_f32_fp8((int)v.x, true);  a[2] += f.x; a[3] += f.y;
  f = __builtin_amdgcn_cvt_pk_f32_fp8((int)v.y, false); a[4] += f.x; a[5] += f.y;
  f = __builtin_amdgcn_cvt_pk_f32_fp8((int)v.y, true);  a[6] += f.x; a[7] += f.y;
}

// ELL row slot-transposed (R15 keying): entry j at (j&3)*8 + (j>>2); slot s's
// 8 entries (j = 4k+s) are the contiguous ushorts [s*8, s*8+8).
__device__ __forceinline__ void ell_insert(int dst, int src, int* cursor,
                                           ushort* ell, unsigned* spill,
                                           int* spillCnt) {
  const int slot = atomicAdd(&cursor[(size_t)dst * kCurStride], 1);
  if (slot < kEllW) {
    ell[(size_t)dst * kEllW + ((slot & 3) << 3) + (slot >> 2)] = (ushort)src;
  } else {
    const int sp = atomicAdd(spillCnt, 1);
    if (sp < kSpillCap) spill[sp] = ((unsigned)dst << 16) | (unsigned)src;
  }
}

// --- mega2: partition (+cursor zero) || prep (bf16 + fp8 pack) ---------------
__global__ void __launch_bounds__(256)
mega2_kernel(const int* __restrict__ ei, const float* __restrict__ x,
             const float* __restrict__ Wl, const float* __restrict__ Wr,
             uint4* __restrict__ xh4, uint2* __restrict__ xq2,
             uint4* __restrict__ wh4, unsigned* __restrict__ stg,
             int* __restrict__ cnt, int* __restrict__ cursor,
             unsigned* __restrict__ spill, int* __restrict__ spillCnt) {
  const int p = blockIdx.x >> 2;
  const int r = blockIdx.x & 3;
  if (r == 0) {
    // zero padded cursor (200000 uint4 over 782x256 threads) + spillCnt
    const int zi = p * 256 + threadIdx.x;
    if (zi < 200000) reinterpret_cast<uint4*>(cursor)[zi] = make_uint4(0, 0, 0, 0);
    if (zi == 0) *spillCnt = 0;
    // ---- partition chunk p via LDS counters (no global contention) ----
    __shared__ int lcnt[8];
    if (threadIdx.x < 8) lcnt[threadIdx.x] = 0;
    __syncthreads();
    const int base = p * 1024 + threadIdx.x;
    int d[4], s[4];
#pragma unroll
    for (int k = 0; k < 4; ++k) {
      const int e = base + k * 256;
      const bool v = e < kEdges;
      d[k] = v ? ei[kEdges + e] : -1;
      s[k] = v ? ei[e] : 0;
    }
#pragma unroll
    for (int k = 0; k < 4; ++k) {
      if (d[k] >= 0) {
        const int b = d[k] / kBktRange;
        const int pos = atomicAdd(&lcnt[b], 1);
        if (pos < kStgCap) {
          stg[((size_t)p * 8 + b) * kStgCap + pos] =
              ((unsigned)d[k] << 16) | (unsigned)s[k];
        } else {  // ~impossible (6 sigma); spill-only (no cursor race)
          const int sp = atomicAdd(spillCnt, 1);
          if (sp < kSpillCap)
            spill[sp] = ((unsigned)d[k] << 16) | (unsigned)s[k];
        }
      }
    }
    __syncthreads();
    if (threadIdx.x < 8)
      cnt[p * 8 + threadIdx.x] = min(lcnt[threadIdx.x], kStgCap);
    return;
  }
  // ---- prep: bf16 + fp8 pack of x, bf16 pack of W=[Wl|Wr] ----
  constexpr int kCvt = kNodes * kF / 8;     // 600000
  const int pid = p * 3 + (r - 1);          // 0..2345
  for (int i = pid * 256 + threadIdx.x; i < kPrepItems; i += kPrepStride) {
    if (i < kCvt) {
      const float4 v0 = reinterpret_cast<const float4*>(x)[i * 2];
      const float4 v1 = reinterpret_cast<const float4*>(x)[i * 2 + 1];
      uint4 o;
      o.x = pack2_bf16(v0.x, v0.y);
      o.y = pack2_bf16(v0.z, v0.w);
      o.z = pack2_bf16(v1.x, v1.y);
      o.w = pack2_bf16(v1.z, v1.w);
      xh4[i] = o;
      int u0 = __builtin_amdgcn_cvt_pk_fp8_f32(v0.x, v0.y, 0, false);
      u0 = __builtin_amdgcn_cvt_pk_fp8_f32(v0.z, v0.w, u0, true);
      int u1 = __builtin_amdgcn_cvt_pk_fp8_f32(v1.x, v1.y, 0, false);
      u1 = __builtin_amdgcn_cvt_pk_fp8_f32(v1.z, v1.w, u1, true);
      xq2[i] = make_uint2((unsigned)u0, (unsigned)u1);
    } else {
      const int j = i - kCvt;
      const int row = j / 24, chunk = j % 24;
      const float* src = (chunk < 12) ? (Wl + (size_t)row * kF + chunk * 8)
                                      : (Wr + (size_t)row * kF + (chunk - 12) * 8);
      const float4 v0 = reinterpret_cast<const float4*>(src)[0];
      const float4 v1 = reinterpret_cast<const float4*>(src)[1];
      uint4 o;
      o.x = pack2_bf16(v0.x, v0.y);
      o.y = pack2_bf16(v0.z, v0.w);
      o.z = pack2_bf16(v1.x, v1.y);
      o.w = pack2_bf16(v1.z, v1.w);
      wh4[j] = o;
    }
  }
}

// --- fillp: XCD-aligned ELL build from compacted lists -----------------------
__global__ void __launch_bounds__(256)
fillp_kernel(const unsigned* __restrict__ stg, const int* __restrict__ cnt,
             int* __restrict__ cursor, ushort* __restrict__ ell,
             unsigned* __restrict__ spill, int* __restrict__ spillCnt) {
  const int g = blockIdx.x & 7;
  for (int chunk = blockIdx.x >> 3; chunk < kChunksP; chunk += gridDim.x >> 3) {
    const int n = cnt[chunk * 8 + g];
    const unsigned* reg = stg + ((size_t)chunk * 8 + g) * kStgCap;
    for (int i = threadIdx.x; i < n; i += 256) {
      const unsigned pr = reg[i];
      ell_insert((int)(pr >> 16), (int)(pr & 0xffffu), cursor, ell, spill,
                 spillCnt);
    }
  }
}

// --- fused gather(fp8, R15 geometry) + MFMA, 4 waves per 16-node tile --------
// Gather: 4 edge-slots x 12 chunk-lanes; lane loads uint2 = 8 fp8 feats.
// Per wave: 4 nodes in 2 rounds of 2 (R15's proven ILP). Combine: +24, +12.
__global__ void __launch_bounds__(256)
gm_kernel(const uint2* __restrict__ xq2, const uint4* __restrict__ xh4,
          const int* __restrict__ cursor, const ushort* __restrict__ ell,
          const unsigned* __restrict__ spill, const int* __restrict__ spillCnt,
          const uint4* __restrict__ wh4, const float* __restrict__ bl,
          float* __restrict__ out) {
  __shared__ __align__(16) short sAgg[16 * kRowS];   // 16 rows x 208 B
  __shared__ float sP[4][4][4];                      // [wave][q][reg]

  const int wave = threadIdx.x >> 6, lane = threadIdx.x & 63;
  const int g = blockIdx.x & 7;
  const int j = blockIdx.x >> 3;
  const int tstart = (g * 3125) >> 3;
  const int tend = ((g + 1) * 3125) >> 3;
  const int tile = tstart + j;
  if (tile >= tend) return;
  const int base = tile * 16;

  const int slot = lane / 12;
  const int c = lane % 12;
  const bool gactive = lane < 48;
  const int slotc = gactive ? slot : 0;
  const int sc = min(*spillCnt, kSpillCap);  // ~always 0

#pragma unroll
  for (int it = 0; it < 2; ++it) {
    const int nA = base + wave * 4 + it * 2;
    const int nB = nA + 1;
    const int degA = cursor[(size_t)nA * kCurStride];
    const int degB = cursor[(size_t)nB * kCurStride];
    const int dmA = min(degA, kEllW);
    const int dmB = min(degB, kEllW);

    // one 16B index load per node: slot s's entries = ushorts [s*8, s*8+8)
    const uint4 ivA = *reinterpret_cast<const uint4*>(
        ell + (size_t)nA * kEllW + (slotc << 3));
    const uint4 ivB = *reinterpret_cast<const uint4*>(
        ell + (size_t)nB * kEllW + (slotc << 3));
    const unsigned wa[4] = {ivA.x, ivA.y, ivA.z, ivA.w};
    const unsigned wb[4] = {ivB.x, ivB.y, ivB.z, ivB.w};

    float a[8] = {0.f, 0.f, 0.f, 0.f, 0.f, 0.f, 0.f, 0.f};
    float b[8] = {0.f, 0.f, 0.f, 0.f, 0.f, 0.f, 0.f, 0.f};

#pragma unroll
    for (int k = 0; k < 8; ++k) {
      const int idx = (k << 2) + slot;   // original ELL position
      const int srcA = (k & 1) ? (int)(wa[k >> 1] >> 16) : (int)(wa[k >> 1] & 0xffffu);
      const int srcB = (k & 1) ? (int)(wb[k >> 1] >> 16) : (int)(wb[k >> 1] & 0xffffu);
      if (gactive && idx < dmA) acc8_fp8(xq2[(size_t)srcA * 12 + c], a);
      if (gactive && idx < dmB) acc8_fp8(xq2[(size_t)srcB * 12 + c], b);
    }
    // spill edges (rare)
    for (int jj = 0; jj < sc; ++jj) {
      const unsigned pr = spill[jj];
      const int pd = (int)(pr >> 16);
      if (lane < 12 && (pd == nA || pd == nB)) {
        const uint2 v = xq2[(size_t)(pr & 0xffffu) * 12 + c];
        if (pd == nA) acc8_fp8(v, a); else acc8_fp8(v, b);
      }
    }
    // combine 4 slots -> lanes 0..11 (2 rounds)
#pragma unroll
    for (int f = 0; f < 8; ++f) {
      a[f] += __shfl(a[f], lane + 24, 64);
      b[f] += __shfl(b[f], lane + 24, 64);
    }
#pragma unroll
    for (int f = 0; f < 8; ++f) {
      a[f] += __shfl(a[f], lane + 12, 64);
      b[f] += __shfl(b[f], lane + 12, 64);
    }

    if (lane < 12) {
      const float invA = 1.0f / fmaxf((float)degA, 1.0f);
      uint4 o;
      o.x = pack2_bf16(a[0] * invA, a[1] * invA);
      o.y = pack2_bf16(a[2] * invA, a[3] * invA);
      o.z = pack2_bf16(a[4] * invA, a[5] * invA);
      o.w = pack2_bf16(a[6] * invA, a[7] * invA);
      *reinterpret_cast<uint4*>(&sAgg[(wave * 4 + it * 2) * kRowS + c * 8]) = o;
      const float invB = 1.0f / fmaxf((float)degB, 1.0f);
      uint4 p;
      p.x = pack2_bf16(b[0] * invB, b[1] * invB);
      p.y = pack2_bf16(b[2] * invB, b[3] * invB);
      p.z = pack2_bf16(b[4] * invB, b[5] * invB);
      p.w = pack2_bf16(b[6] * invB, b[7] * invB);
      *reinterpret_cast<uint4*>(&sAgg[(wave * 4 + it * 2 + 1) * kRowS + c * 8]) = p;
    }
  }
  __syncthreads();

  // ---- phase B: MFMA, wave w owns channel-groups {2w, 2w+1} ----
  const int r = lane & 15, q = lane >> 4;
  const int cg0 = wave * 2;
  const short8* xhS = reinterpret_cast<const short8*>(xh4);
  const short8* whS = reinterpret_cast<const short8*>(wh4);

  floatx4 fac[2] = {};
#pragma unroll
  for (int ks = 0; ks < 6; ++ks) {
    short8 a;
    if (ks < 3) {
      a = *reinterpret_cast<const short8*>(&sAgg[r * kRowS + (ks * 4 + q) * 8]);
    } else {
      a = xhS[(size_t)(base + r) * 12 + (ks - 3) * 4 + q];
    }
#pragma unroll
    for (int i = 0; i < 2; ++i) {
      const short8 b = whS[((cg0 + i) * 16 + r) * 24 + ks * 4 + q];
      fac[i] = __builtin_amdgcn_mfma_f32_16x16x32_bf16(a, b, fac[i], 0, 0, 0);
    }
  }

  float p0 = 0.f, p1 = 0.f, p2 = 0.f, p3 = 0.f;
#pragma unroll
  for (int i = 0; i < 2; ++i) {
    const float bb = bl[(cg0 + i) * 16 + r];
    fac[i][0] += bb; fac[i][1] += bb; fac[i][2] += bb; fac[i][3] += bb;
    p0 += fac[i][0] * fac[i][0];
    p1 += fac[i][1] * fac[i][1];
    p2 += fac[i][2] * fac[i][2];
    p3 += fac[i][3] * fac[i][3];
  }
#pragma unroll
  for (int off = 1; off < 16; off <<= 1) {
    p0 += __shfl_xor(p0, off, 64);
    p1 += __shfl_xor(p1, off, 64);
    p2 += __shfl_xor(p2, off, 64);
    p3 += __shfl_xor(p3, off, 64);
  }
  if (r == 0) {
    sP[wave][q][0] = p0; sP[wave][q][1] = p1;
    sP[wave][q][2] = p2; sP[wave][q][3] = p3;
  }
  __syncthreads();
  const float t0 = sP[0][q][0] + sP[1][q][0] + sP[2][q][0] + sP[3][q][0];
  const float t1 = sP[0][q][1] + sP[1][q][1] + sP[2][q][1] + sP[3][q][1];
  const float t2 = sP[0][q][2] + sP[1][q][2] + sP[2][q][2] + sP[3][q][2];
  const float t3 = sP[0][q][3] + sP[1][q][3] + sP[2][q][3] + sP[3][q][3];
  const float s0 = 1.0f / fmaxf(sqrtf(t0), 1e-12f);
  const float s1 = 1.0f / fmaxf(sqrtf(t1), 1e-12f);
  const float s2 = 1.0f / fmaxf(sqrtf(t2), 1e-12f);
  const float s3 = 1.0f / fmaxf(sqrtf(t3), 1e-12f);

#pragma unroll
  for (int i = 0; i < 2; ++i) {
    const int col = (cg0 + i) * 16 + r;
    float* o = out + (size_t)(base + q * 4) * kH + col;
    o[0 * kH] = fac[i][0] * s0;
    o[1 * kH] = fac[i][1] * s1;
    o[2 * kH] = fac[i][2] * s2;
    o[3 * kH] = fac[i][3] * s3;
  }
}

extern "C" void kernel_launch(void* const* d_in, const int* in_sizes, int n_in,
                              void* d_out, int out_size, void* d_ws, size_t ws_size,
                              hipStream_t stream) {
  const int*   ei = (const int*)d_in[0];
  const float* x  = (const float*)d_in[1];
  const float* Wl = (const float*)d_in[2];
  const float* bl = (const float*)d_in[3];
  const float* Wr = (const float*)d_in[4];
  float* out = (float*)d_out;

  char* ws = (char*)d_ws;
  uint4*    xh4      = (uint4*)(ws + kXhOff);
  uint2*    xq2      = (uint2*)(ws + kXqOff);
  unsigned* stg      = (unsigned*)(ws + kStgOff);
  uint4*    wh4      = (uint4*)(ws + kWhOff);
  ushort*   ell      = (ushort*)(ws + kEllOff);
  int*      cursor   = (int*)(ws + kCurOff);
  int*      spillCnt = (int*)(ws + kSpcOff);
  unsigned* spill    = (unsigned*)(ws + kSpillOff);
  int*      cnt      = (int*)(ws + kCntOff);

  mega2_kernel<<<kMega2Blocks, 256, 0, stream>>>(
      ei, x, Wl, Wr, xh4, xq2, wh4, stg, cnt, cursor, spill, spillCnt);

  fillp_kernel<<<3128, 256, 0, stream>>>(stg, cnt, cursor, ell, spill, spillCnt);

  gm_kernel<<<3128, 256, 0, stream>>>(xq2, xh4, cursor, ell, spill, spillCnt,
                                      wh4, bl, out);
}

// Round 21
// 94.879 us; speedup vs baseline: 1.1188x; 1.0170x over previous
//
#include <hip/hip_runtime.h>

// SAGEConv (mean aggr, root weight, L2 normalize), fp32 in/out.
// R21: front-end rebalance — prep split across BOTH front kernels so each
// dispatch pairs a latency-bound job with a BW-bound one:
//   mega2  = partition ∥ prep[0,half)      (period 2)
//   fillp2 = ELL-fill  ∥ prep[half,end)    (period 16, fill g=blockIdx&7)
//   gm     = R20's fused fp8-gather + MFMA (unchanged).

typedef __attribute__((ext_vector_type(8))) short short8;   // 8 bf16 = 4 VGPRs
typedef __attribute__((ext_vector_type(4))) float floatx4;  // MFMA acc
typedef __attribute__((ext_vector_type(2))) float floatx2;  // fp8 cvt result

constexpr int kNodes = 50000;
constexpr int kEdges = 800000;
constexpr int kF = 96;          // input features
constexpr int kH = 128;         // output features
constexpr int kEllW = 32;       // ELL width
constexpr int kSpillCap = 4096;
constexpr int kBktRange = kNodes / 8;  // 6250 nodes per XCD-group
constexpr int kCurStride = 16;  // cursor stride in ints: 1 counter per 64B line
constexpr int kChunksP = 782;   // partition chunks (1024 edges each)
constexpr int kStgCap = 192;    // per-(chunk,bucket) cap (mean 128 + 6 sigma)

// workspace byte offsets
constexpr size_t kXhOff    = 0;          // 9,600,000  bf16 table (MFMA x-half)
constexpr size_t kXqOff    = 9600000;    // 4,800,000  fp8 table (gather)
constexpr size_t kStgOff   = 14400000;   // 4,804,608  partition staging
constexpr size_t kWhOff    = 19204608;   // 49,152     bf16 weights
constexpr size_t kEllOff   = 19253760;   // 3,200,000  ELL (ushort)
constexpr size_t kCurOff   = 22453760;   // 3,200,000  padded cursor
constexpr size_t kSpcOff   = 25653760;   // 4          spillCnt
constexpr size_t kSpillOff = 25653776;   // 16,384     spill list
constexpr size_t kCntOff   = 25670160;   // 25,024     per-(chunk,bucket) counts

constexpr int kPrepItems = kNodes * kF / 8 + kH * 192 / 8;  // 603072
constexpr int kPrepSplit = 301568;   // first-half item count (mult of 256)

constexpr int kRowS = 104;   // LDS agg row stride in shorts (208 B)

__device__ __forceinline__ unsigned pack2_bf16(float a, float b) {
  unsigned ua = __float_as_uint(a), ub = __float_as_uint(b);
  ua = (ua + 0x7fffu + ((ua >> 16) & 1u)) >> 16;   // RNE
  ub = (ub + 0x7fffu + ((ub >> 16) & 1u)) >> 16;
  return ua | (ub << 16);
}

// decode 8 fp8 (one uint2) and accumulate into a[0..7]
__device__ __forceinline__ void acc8_fp8(const uint2 v, float* a) {
  floatx2 f;
  f = __builtin_amdgcn_cvt_pk_f32_fp8((int)v.x, false); a[0] += f.x; a[1] += f.y;
  f = __builtin_amdgcn_cvt_pk_f32_fp8((int)v.x, true);  a[2] += f.x; a[3] += f.y;
  f = __builtin_amdgcn_cvt_pk_f32_fp8((int)v.y, false); a[4] += f.x; a[5] += f.y;
  f = __builtin_amdgcn_cvt_pk_f32_fp8((int)v.y, true);  a[6] += f.x; a[7] += f.y;
}

// one prep item: i < kCvt -> pack x row-chunk to bf16 + fp8; else W chunk.
__device__ __forceinline__ void prep_item(int i, const float* __restrict__ x,
                                          const float* __restrict__ Wl,
                                          const float* __restrict__ Wr,
                                          uint4* __restrict__ xh4,
                                          uint2* __restrict__ xq2,
                                          uint4* __restrict__ wh4) {
  constexpr int kCvt = kNodes * kF / 8;     // 600000
  if (i < kCvt) {
    const float4 v0 = reinterpret_cast<const float4*>(x)[i * 2];
    const float4 v1 = reinterpret_cast<const float4*>(x)[i * 2 + 1];
    uint4 o;
    o.x = pack2_bf16(v0.x, v0.y);
    o.y = pack2_bf16(v0.z, v0.w);
    o.z = pack2_bf16(v1.x, v1.y);
    o.w = pack2_bf16(v1.z, v1.w);
    xh4[i] = o;
    int u0 = __builtin_amdgcn_cvt_pk_fp8_f32(v0.x, v0.y, 0, false);
    u0 = __builtin_amdgcn_cvt_pk_fp8_f32(v0.z, v0.w, u0, true);
    int u1 = __builtin_amdgcn_cvt_pk_fp8_f32(v1.x, v1.y, 0, false);
    u1 = __builtin_amdgcn_cvt_pk_fp8_f32(v1.z, v1.w, u1, true);
    xq2[i] = make_uint2((unsigned)u0, (unsigned)u1);
  } else {
    const int j = i - kCvt;
    const int row = j / 24, chunk = j % 24;
    const float* src = (chunk < 12) ? (Wl + (size_t)row * kF + chunk * 8)
                                    : (Wr + (size_t)row * kF + (chunk - 12) * 8);
    const float4 v0 = reinterpret_cast<const float4*>(src)[0];
    const float4 v1 = reinterpret_cast<const float4*>(src)[1];
    uint4 o;
    o.x = pack2_bf16(v0.x, v0.y);
    o.y = pack2_bf16(v0.z, v0.w);
    o.z = pack2_bf16(v1.x, v1.y);
    o.w = pack2_bf16(v1.z, v1.w);
    wh4[j] = o;
  }
}

// ELL row slot-transposed (R15 keying): entry j at (j&3)*8 + (j>>2); slot s's
// 8 entries (j = 4k+s) are the contiguous ushorts [s*8, s*8+8).
__device__ __forceinline__ void ell_insert(int dst, int src, int* cursor,
                                           ushort* ell, unsigned* spill,
                                           int* spillCnt) {
  const int slot = atomicAdd(&cursor[(size_t)dst * kCurStride], 1);
  if (slot < kEllW) {
    ell[(size_t)dst * kEllW + ((slot & 3) << 3) + (slot >> 2)] = (ushort)src;
  } else {
    const int sp = atomicAdd(spillCnt, 1);
    if (sp < kSpillCap) spill[sp] = ((unsigned)dst << 16) | (unsigned)src;
  }
}

// --- mega2: partition (+cursor zero) ∥ prep[0, kPrepSplit) — period 2 --------
__global__ void __launch_bounds__(256)
mega2_kernel(const int* __restrict__ ei, const float* __restrict__ x,
             const float* __restrict__ Wl, const float* __restrict__ Wr,
             uint4* __restrict__ xh4, uint2* __restrict__ xq2,
             uint4* __restrict__ wh4, unsigned* __restrict__ stg,
             int* __restrict__ cnt, int* __restrict__ cursor,
             unsigned* __restrict__ spill, int* __restrict__ spillCnt) {
  const int p = blockIdx.x >> 1;
  if ((blockIdx.x & 1) == 0) {
    // zero padded cursor (200000 uint4 across 782 blocks) + spillCnt
    const int zi = p * 256 + threadIdx.x;
    if (zi < 200000) reinterpret_cast<uint4*>(cursor)[zi] = make_uint4(0, 0, 0, 0);
    if (zi == 0) *spillCnt = 0;
    // partition chunk p via LDS counters (no global contention)
    __shared__ int lcnt[8];
    if (threadIdx.x < 8) lcnt[threadIdx.x] = 0;
    __syncthreads();
    const int base = p * 1024 + threadIdx.x;
    int d[4], s[4];
#pragma unroll
    for (int k = 0; k < 4; ++k) {
      const int e = base + k * 256;
      const bool v = e < kEdges;
      d[k] = v ? ei[kEdges + e] : -1;
      s[k] = v ? ei[e] : 0;
    }
#pragma unroll
    for (int k = 0; k < 4; ++k) {
      if (d[k] >= 0) {
        const int b = d[k] / kBktRange;
        const int pos = atomicAdd(&lcnt[b], 1);
        if (pos < kStgCap) {
          stg[((size_t)p * 8 + b) * kStgCap + pos] =
              ((unsigned)d[k] << 16) | (unsigned)s[k];
        } else {  // ~impossible (6 sigma); spill-only (no cursor race)
          const int sp = atomicAdd(spillCnt, 1);
          if (sp < kSpillCap)
            spill[sp] = ((unsigned)d[k] << 16) | (unsigned)s[k];
        }
      }
    }
    __syncthreads();
    if (threadIdx.x < 8)
      cnt[p * 8 + threadIdx.x] = min(lcnt[threadIdx.x], kStgCap);
    return;
  }
  // prep first half: items [0, kPrepSplit), stride 782*256
  for (int i = p * 256 + threadIdx.x; i < kPrepSplit; i += kChunksP * 256)
    prep_item(i, x, Wl, Wr, xh4, xq2, wh4);
}

// --- fillp2: ELL fill (XCD-aligned) ∥ prep[kPrepSplit, end) — period 16 ------
__global__ void __launch_bounds__(256)
fillp2_kernel(const unsigned* __restrict__ stg, const int* __restrict__ cnt,
              int* __restrict__ cursor, ushort* __restrict__ ell,
              unsigned* __restrict__ spill, int* __restrict__ spillCnt,
              const float* __restrict__ x, const float* __restrict__ Wl,
              const float* __restrict__ Wr, uint4* __restrict__ xh4,
              uint2* __restrict__ xq2, uint4* __restrict__ wh4) {
  const int q = blockIdx.x >> 4;     // 0..390
  const int r = blockIdx.x & 15;
  if (r < 8) {
    const int g = r;                 // == blockIdx&7 -> XCD-aligned
#pragma unroll
    for (int half = 0; half < 2; ++half) {
      const int chunk = q + half * 391;   // covers 0..781
      const int n = cnt[chunk * 8 + g];
      const unsigned* reg = stg + ((size_t)chunk * 8 + g) * kStgCap;
      for (int i = threadIdx.x; i < n; i += 256) {
        const unsigned pr = reg[i];
        ell_insert((int)(pr >> 16), (int)(pr & 0xffffu), cursor, ell, spill,
                   spillCnt);
      }
    }
    return;
  }
  // prep second half: 3128 slots cover [kPrepSplit, kPrepItems) in one pass
  const int pid = q * 8 + (r - 8);   // 0..3127
  const int i = kPrepSplit + pid * 256 + threadIdx.x;
  if (i < kPrepItems) prep_item(i, x, Wl, Wr, xh4, xq2, wh4);
}

// --- fused gather(fp8, R15 geometry) + MFMA, 4 waves per 16-node tile --------
__global__ void __launch_bounds__(256)
gm_kernel(const uint2* __restrict__ xq2, const uint4* __restrict__ xh4,
          const int* __restrict__ cursor, const ushort* __restrict__ ell,
          const unsigned* __restrict__ spill, const int* __restrict__ spillCnt,
          const uint4* __restrict__ wh4, const float* __restrict__ bl,
          float* __restrict__ out) {
  __shared__ __align__(16) short sAgg[16 * kRowS];   // 16 rows x 208 B
  __shared__ float sP[4][4][4];                      // [wave][q][reg]

  const int wave = threadIdx.x >> 6, lane = threadIdx.x & 63;
  const int g = blockIdx.x & 7;
  const int j = blockIdx.x >> 3;
  const int tstart = (g * 3125) >> 3;
  const int tend = ((g + 1) * 3125) >> 3;
  const int tile = tstart + j;
  if (tile >= tend) return;
  const int base = tile * 16;

  const int slot = lane / 12;
  const int c = lane % 12;
  const bool gactive = lane < 48;
  const int slotc = gactive ? slot : 0;
  const int sc = min(*spillCnt, kSpillCap);  // ~always 0

#pragma unroll
  for (int it = 0; it < 2; ++it) {
    const int nA = base + wave * 4 + it * 2;
    const int nB = nA + 1;
    const int degA = cursor[(size_t)nA * kCurStride];
    const int degB = cursor[(size_t)nB * kCurStride];
    const int dmA = min(degA, kEllW);
    const int dmB = min(degB, kEllW);

    const uint4 ivA = *reinterpret_cast<const uint4*>(
        ell + (size_t)nA * kEllW + (slotc << 3));
    const uint4 ivB = *reinterpret_cast<const uint4*>(
        ell + (size_t)nB * kEllW + (slotc << 3));
    const unsigned wa[4] = {ivA.x, ivA.y, ivA.z, ivA.w};
    const unsigned wb[4] = {ivB.x, ivB.y, ivB.z, ivB.w};

    float a[8] = {0.f, 0.f, 0.f, 0.f, 0.f, 0.f, 0.f, 0.f};
    float b[8] = {0.f, 0.f, 0.f, 0.f, 0.f, 0.f, 0.f, 0.f};

#pragma unroll
    for (int k = 0; k < 8; ++k) {
      const int idx = (k << 2) + slot;   // original ELL position
      const int srcA = (k & 1) ? (int)(wa[k >> 1] >> 16) : (int)(wa[k >> 1] & 0xffffu);
      const int srcB = (k & 1) ? (int)(wb[k >> 1] >> 16) : (int)(wb[k >> 1] & 0xffffu);
      if (gactive && idx < dmA) acc8_fp8(xq2[(size_t)srcA * 12 + c], a);
      if (gactive && idx < dmB) acc8_fp8(xq2[(size_t)srcB * 12 + c], b);
    }
    for (int jj = 0; jj < sc; ++jj) {
      const unsigned pr = spill[jj];
      const int pd = (int)(pr >> 16);
      if (lane < 12 && (pd == nA || pd == nB)) {
        const uint2 v = xq2[(size_t)(pr & 0xffffu) * 12 + c];
        if (pd == nA) acc8_fp8(v, a); else acc8_fp8(v, b);
      }
    }
#pragma unroll
    for (int f = 0; f < 8; ++f) {
      a[f] += __shfl(a[f], lane + 24, 64);
      b[f] += __shfl(b[f], lane + 24, 64);
    }
#pragma unroll
    for (int f = 0; f < 8; ++f) {
      a[f] += __shfl(a[f], lane + 12, 64);
      b[f] += __shfl(b[f], lane + 12, 64);
    }

    if (lane < 12) {
      const float invA = 1.0f / fmaxf((float)degA, 1.0f);
      uint4 o;
      o.x = pack2_bf16(a[0] * invA, a[1] * invA);
      o.y = pack2_bf16(a[2] * invA, a[3] * invA);
      o.z = pack2_bf16(a[4] * invA, a[5] * invA);
      o.w = pack2_bf16(a[6] * invA, a[7] * invA);
      *reinterpret_cast<uint4*>(&sAgg[(wave * 4 + it * 2) * kRowS + c * 8]) = o;
      const float invB = 1.0f / fmaxf((float)degB, 1.0f);
      uint4 p;
      p.x = pack2_bf16(b[0] * invB, b[1] * invB);
      p.y = pack2_bf16(b[2] * invB, b[3] * invB);
      p.z = pack2_bf16(b[4] * invB, b[5] * invB);
      p.w = pack2_bf16(b[6] * invB, b[7] * invB);
      *reinterpret_cast<uint4*>(&sAgg[(wave * 4 + it * 2 + 1) * kRowS + c * 8]) = p;
    }
  }
  __syncthreads();

  // ---- phase B: MFMA, wave w owns channel-groups {2w, 2w+1} ----
  const int r = lane & 15, q2 = lane >> 4;
  const int cg0 = wave * 2;
  const short8* xhS = reinterpret_cast<const short8*>(xh4);
  const short8* whS = reinterpret_cast<const short8*>(wh4);

  floatx4 fac[2] = {};
#pragma unroll
  for (int ks = 0; ks < 6; ++ks) {
    short8 a;
    if (ks < 3) {
      a = *reinterpret_cast<const short8*>(&sAgg[r * kRowS + (ks * 4 + q2) * 8]);
    } else {
      a = xhS[(size_t)(base + r) * 12 + (ks - 3) * 4 + q2];
    }
#pragma unroll
    for (int i = 0; i < 2; ++i) {
      const short8 b = whS[((cg0 + i) * 16 + r) * 24 + ks * 4 + q2];
      fac[i] = __builtin_amdgcn_mfma_f32_16x16x32_bf16(a, b, fac[i], 0, 0, 0);
    }
  }

  float p0 = 0.f, p1 = 0.f, p2 = 0.f, p3 = 0.f;
#pragma unroll
  for (int i = 0; i < 2; ++i) {
    const float bb = bl[(cg0 + i) * 16 + r];
    fac[i][0] += bb; fac[i][1] += bb; fac[i][2] += bb; fac[i][3] += bb;
    p0 += fac[i][0] * fac[i][0];
    p1 += fac[i][1] * fac[i][1];
    p2 += fac[i][2] * fac[i][2];
    p3 += fac[i][3] * fac[i][3];
  }
#pragma unroll
  for (int off = 1; off < 16; off <<= 1) {
    p0 += __shfl_xor(p0, off, 64);
    p1 += __shfl_xor(p1, off, 64);
    p2 += __shfl_xor(p2, off, 64);
    p3 += __shfl_xor(p3, off, 64);
  }
  if (r == 0) {
    sP[wave][q2][0] = p0; sP[wave][q2][1] = p1;
    sP[wave][q2][2] = p2; sP[wave][q2][3] = p3;
  }
  __syncthreads();
  const float t0 = sP[0][q2][0] + sP[1][q2][0] + sP[2][q2][0] + sP[3][q2][0];
  const float t1 = sP[0][q2][1] + sP[1][q2][1] + sP[2][q2][1] + sP[3][q2][1];
  const float t2 = sP[0][q2][2] + sP[1][q2][2] + sP[2][q2][2] + sP[3][q2][2];
  const float t3 = sP[0][q2][3] + sP[1][q2][3] + sP[2][q2][3] + sP[3][q2][3];
  const float s0 = 1.0f / fmaxf(sqrtf(t0), 1e-12f);
  const float s1 = 1.0f / fmaxf(sqrtf(t1), 1e-12f);
  const float s2 = 1.0f / fmaxf(sqrtf(t2), 1e-12f);
  const float s3 = 1.0f / fmaxf(sqrtf(t3), 1e-12f);

#pragma unroll
  for (int i = 0; i < 2; ++i) {
    const int col = (cg0 + i) * 16 + r;
    float* o = out + (size_t)(base + q2 * 4) * kH + col;
    o[0 * kH] = fac[i][0] * s0;
    o[1 * kH] = fac[i][1] * s1;
    o[2 * kH] = fac[i][2] * s2;
    o[3 * kH] = fac[i][3] * s3;
  }
}

extern "C" void kernel_launch(void* const* d_in, const int* in_sizes, int n_in,
                              void* d_out, int out_size, void* d_ws, size_t ws_size,
                              hipStream_t stream) {
  const int*   ei = (const int*)d_in[0];
  const float* x  = (const float*)d_in[1];
  const float* Wl = (const float*)d_in[2];
  const float* bl = (const float*)d_in[3];
  const float* Wr = (const float*)d_in[4];
  float* out = (float*)d_out;

  char* ws = (char*)d_ws;
  uint4*    xh4      = (uint4*)(ws + kXhOff);
  uint2*    xq2      = (uint2*)(ws + kXqOff);
  unsigned* stg      = (unsigned*)(ws + kStgOff);
  uint4*    wh4      = (uint4*)(ws + kWhOff);
  ushort*   ell      = (ushort*)(ws + kEllOff);
  int*      cursor   = (int*)(ws + kCurOff);
  int*      spillCnt = (int*)(ws + kSpcOff);
  unsigned* spill    = (unsigned*)(ws + kSpillOff);
  int*      cnt      = (int*)(ws + kCntOff);

  mega2_kernel<<<kChunksP * 2, 256, 0, stream>>>(
      ei, x, Wl, Wr, xh4, xq2, wh4, stg, cnt, cursor, spill, spillCnt);

  fillp2_kernel<<<391 * 16, 256, 0, stream>>>(
      stg, cnt, cursor, ell, spill, spillCnt, x, Wl, Wr, xh4, xq2, wh4);

  gm_kernel<<<3128, 256, 0, stream>>>(xq2, xh4, cursor, ell, spill, spillCnt,
                                      wh4, bl, out);
}